// Round 7
// baseline (631.120 us; speedup 1.0000x reference)
//
#include <hip/hip_runtime.h>

// ============================================================================
// KnowledgeGraphEncoder: 2-layer dense GAT, N=4096, H=4.
// bf16 MFMA merged projection GEMMs; MX-fp8 (e4m3, unit scales) mfma_scale
// 16x16x128 attention GEMMs; single-pass pexp with analytic row-max bound +
// 1-bit adjacency bitmask; fused 8-way s-kernels.
// R6-R10: gemm_proj = 256x256 8-phase schedule, register reuse, vmcnt at
// P4/P8 only (m201 discipline). Best: 74->71us L1 proj.
// R11: gemm_mx ported to the same proven structure — 256x128 tile, 512 thr /
// 8 waves (2Mx4N), per-wave 128x32, quadrant order (A0,B0)->(A0,B1)->
// (A1,B1)->(A1,B0), aR[4]/bR[2] register reuse (20 b128/wave/K-tile),
// one half-stage per phase, vmcnt(3) at P4/P8 only (ledger: stA=2,stB=1).
// LDS 96KB -> 1 block/CU. Accumulation order per acc unchanged (bit-exact).
// ============================================================================

typedef unsigned short u16;
typedef unsigned char u8;
typedef unsigned long long u64;
using short8  = __attribute__((ext_vector_type(8))) short;
using float4v = __attribute__((ext_vector_type(4))) float;
using int4v   = __attribute__((ext_vector_type(4))) int;
using int8v   = __attribute__((ext_vector_type(8))) int;

#define NN 4096
#define NHEADS 4

__device__ __forceinline__ u16 f2bf(float f) {
  union { float f; unsigned u; } v; v.f = f;
  unsigned u = v.u;
  return (u16)((u + 0x7FFFu + ((u >> 16) & 1u)) >> 16);   // RNE
}
__device__ __forceinline__ float bf2f(u16 x) {
  union { unsigned u; float f; } v; v.u = ((unsigned)x) << 16; return v.f;
}
// pack 4 floats -> 4 fp8 e4m3 bytes (HW cvt, OCP on gfx950)
__device__ __forceinline__ unsigned pk_fp8x4(float a, float b, float c, float d) {
  int lo = __builtin_amdgcn_cvt_pk_fp8_f32(a, b, 0, false);
  return (unsigned)__builtin_amdgcn_cvt_pk_fp8_f32(c, d, lo, true);
}

// async global->LDS, 16B per lane, LDS dest = wave-uniform base + lane*16
__device__ __forceinline__ void async16(const void* g, void* l) {
  __builtin_amdgcn_global_load_lds(
      (const __attribute__((address_space(1))) unsigned int*)g,
      (__attribute__((address_space(3))) unsigned int*)l, 16, 0, 0);
}

// ---------------------------------------------------------------- cast fp32->bf16
__global__ __launch_bounds__(256) void cast_f32_bf16(const float* __restrict__ in,
                                                     u16* __restrict__ out, int n) {
  int i = blockIdx.x * 256 + threadIdx.x;
  if (i < n) out[i] = f2bf(in[i]);
}

// ------------------------------------------------- adj int32 -> bitmask (1 bit/entry)
__global__ __launch_bounds__(256) void adj2bits(const int* __restrict__ adj,
                                                u64* __restrict__ bits) {
  size_t gw = (size_t)blockIdx.x * 4 + (threadIdx.x >> 6);
  int lane = threadIdx.x & 63;
  int v = adj[gw * 64 + lane];
  u64 b = __ballot(v != 0);
  if (lane == 0) bits[gw] = b;
}

// ------------------------------------------------- transpose+cast fp32 -> bf16
// in [z][R][C] -> out [z][C][R]
__global__ __launch_bounds__(256) void transcast_f32(const float* __restrict__ in,
                                                     u16* __restrict__ out, int R, int C) {
  __shared__ float t[32][33];
  size_t zoff = (size_t)blockIdx.z * R * C;
  in += zoff; out += zoff;
  int c0 = blockIdx.x * 32, r0 = blockIdx.y * 32;
  int tx = threadIdx.x & 31, ty = threadIdx.x >> 5;
#pragma unroll
  for (int i = 0; i < 32; i += 8)
    t[ty + i][tx] = in[(size_t)(r0 + ty + i) * C + (c0 + tx)];
  __syncthreads();
#pragma unroll
  for (int i = 0; i < 32; i += 8)
    out[(size_t)(c0 + ty + i) * R + (r0 + tx)] = f2bf(t[tx][ty + i]);
}

// ------------------------------------------------- wa[side][h][f] = sum_o W[h][f][o]*a[h][side*O+o]
__global__ __launch_bounds__(256) void wa_kernel(const float* __restrict__ W,
                                                 const float* __restrict__ a,
                                                 float* __restrict__ wa, int F, int O) {
  int gw = blockIdx.x * 4 + (threadIdx.x >> 6);
  int lane = threadIdx.x & 63;
  int total = 2 * NHEADS * F;
  if (gw >= total) return;
  int side = gw / (NHEADS * F);
  int rem = gw - side * NHEADS * F;
  int h = rem / F, f = rem - h * F;
  const float* wrow = W + ((size_t)h * F + f) * O;
  const float* av = a + (size_t)h * 2 * O + (size_t)side * O;
  float s = 0.f;
  for (int o = lane; o < O; o += 64) s += wrow[o] * av[o];
#pragma unroll
  for (int off = 32; off > 0; off >>= 1) s += __shfl_down(s, off);
  if (lane == 0) wa[gw] = s;
}

// ------------------------------------------------- fused 8-way s: one wave per node
__global__ __launch_bounds__(256) void s8_kernel_f32(const float* __restrict__ X,
                                                     const float* __restrict__ wa,
                                                     float* __restrict__ sout, int F) {
  int n = blockIdx.x * 4 + (threadIdx.x >> 6);
  int lane = threadIdx.x & 63;
  const float* x = X + (size_t)n * F;
  float acc[8] = {};
  for (int f = lane; f < F; f += 64) {
    float xv = x[f];
#pragma unroll
    for (int k = 0; k < 8; k++) acc[k] += xv * wa[(size_t)k * F + f];
  }
#pragma unroll
  for (int k = 0; k < 8; k++) {
    float s = acc[k];
#pragma unroll
    for (int off = 32; off > 0; off >>= 1) s += __shfl_down(s, off);
    if (lane == 0) sout[(size_t)k * NN + n] = s;
  }
}

__global__ __launch_bounds__(256) void s8_kernel_bf16(const u16* __restrict__ X,
                                                      const float* __restrict__ wa,
                                                      float* __restrict__ sout, int F) {
  int n = blockIdx.x * 4 + (threadIdx.x >> 6);
  int lane = threadIdx.x & 63;
  const u16* x = X + (size_t)n * F;
  float acc[8] = {};
  for (int f = lane; f < F; f += 64) {
    float xv = bf2f(x[f]);
#pragma unroll
    for (int k = 0; k < 8; k++) acc[k] += xv * wa[(size_t)k * F + f];
  }
#pragma unroll
  for (int k = 0; k < 8; k++) {
    float s = acc[k];
#pragma unroll
    for (int off = 32; off > 0; off >>= 1) s += __shfl_down(s, off);
    if (lane == 0) sout[(size_t)k * NN + n] = s;
  }
}

// ------------------------------------------------- sdmax[h] = max_n sdst[h][n]
__global__ __launch_bounds__(256) void sdmax_kernel(const float* __restrict__ s,
                                                    float* __restrict__ out) {
  int h = blockIdx.x, tid = threadIdx.x;
  const float* sd = s + (size_t)(NHEADS + h) * NN;
  float m = -3e38f;
  for (int i = tid; i < NN; i += 256) m = fmaxf(m, sd[i]);
  __shared__ float red[4];
#pragma unroll
  for (int off = 32; off > 0; off >>= 1) m = fmaxf(m, __shfl_down(m, off));
  if ((tid & 63) == 0) red[tid >> 6] = m;
  __syncthreads();
  if (tid == 0) out[h] = fmaxf(fmaxf(red[0], red[1]), fmaxf(red[2], red[3]));
}

// ------------------------------------------------- single-pass G-head P' = exp(v - m') fp8
template <int G>
__global__ __launch_bounds__(256) void pexp_g_kernel(const u64* __restrict__ mb,
                                                     const float* __restrict__ ew,
                                                     const float* __restrict__ s,
                                                     const float* __restrict__ sdmax,
                                                     u8* __restrict__ P,
                                                     float* __restrict__ L, int hb) {
  __shared__ u64 mrow[64];
  __shared__ float lred[G][4];
  int i = blockIdx.x, tid = threadIdx.x;
  if (tid < 64) mrow[tid] = mb[(size_t)i * 64 + tid];
  float sr[G], mp[G], lacc[G];
#pragma unroll
  for (int z = 0; z < G; z++) {
    sr[z] = s[(size_t)(hb + z) * NN + i];
    mp[z] = fmaxf(0.0f, sr[z] + sdmax[hb + z]);
    lacc[z] = 0.f;
  }
  const float4* wrow = (const float4*)(ew + (size_t)i * NN);
  __syncthreads();
  for (int jv = tid; jv < NN / 4; jv += 256) {
    float4 w = wrow[jv];
    int j0 = jv * 4;
    u64 mw = mrow[jv >> 4] >> (j0 & 63);
    float we[4]; we[0] = w.x; we[1] = w.y; we[2] = w.z; we[3] = w.w;
    bool m[4];
#pragma unroll
    for (int k = 0; k < 4; k++) m[k] = ((mw >> k) & 1ull) || (j0 + k == i);
#pragma unroll
    for (int z = 0; z < G; z++) {
      const float4 sd4 = *(const float4*)(s + (size_t)(NHEADS + hb + z) * NN + j0);
      float sd[4]; sd[0] = sd4.x; sd[1] = sd4.y; sd[2] = sd4.z; sd[3] = sd4.w;
      float p[4];
#pragma unroll
      for (int k = 0; k < 4; k++) {
        float x = sr[z] + sd[k];
        float e = x > 0.f ? x : 0.2f * x;
        float v = (m[k] ? e : -9e15f) * we[k];
        p[k] = __expf(v - mp[z]);
        lacc[z] += p[k];
      }
      *(unsigned*)(P + ((size_t)z * NN + i) * NN + j0) = pk_fp8x4(p[0], p[1], p[2], p[3]);
    }
  }
#pragma unroll
  for (int z = 0; z < G; z++) {
    float r = lacc[z];
#pragma unroll
    for (int off = 32; off > 0; off >>= 1) r += __shfl_down(r, off);
    if ((tid & 63) == 0) lred[z][tid >> 6] = r;
  }
  __syncthreads();
  if (tid < G)
    L[(size_t)(hb + tid) * NN + i] = lred[tid][0] + lred[tid][1] + lred[tid][2] + lred[tid][3];
}

// ------------------------------------------------- merged projection GEMM (R10 final)
#define LDA_(CUR, MH)                                                            \
  _Pragma("unroll") for (int mi = 0; mi < 4; mi++) {                             \
    int lr = mi * 32 + wm16 + lm;                                                \
    int sw = lr & 7;                                                             \
    const u16* ap = &LA[CUR][MH][lr * 64];                                       \
    aR[mi][0] = *(const short8*)(ap + ((quad ^ sw) * 8));                        \
    aR[mi][1] = *(const short8*)(ap + (((4 + quad) ^ sw) * 8));                  \
  }

#define LDB_(CUR, NH)                                                            \
  _Pragma("unroll") for (int ni = 0; ni < 2; ni++) {                             \
    int lc = ni * 64 + wn16 + lm;                                                \
    int sw = lc & 7;                                                             \
    const u16* bp = &LB[CUR][NH][lc * 64];                                       \
    bR[NH][ni][0] = *(const short8*)(bp + ((quad ^ sw) * 8));                    \
    bR[NH][ni][1] = *(const short8*)(bp + (((4 + quad) ^ sw) * 8));              \
  }

#define VMW4 asm volatile("s_waitcnt vmcnt(4)" ::: "memory")
#define VMW0 asm volatile("s_waitcnt vmcnt(0)" ::: "memory")

#define PH(MH, NH, LOADA, LOADB, STAGE, WAIT)                                    \
  {                                                                              \
    LOADA;                                                                       \
    LOADB;                                                                       \
    STAGE;                                                                       \
    WAIT;                                                                        \
    __builtin_amdgcn_s_barrier();                                                \
    __builtin_amdgcn_s_setprio(1);                                               \
    _Pragma("unroll") for (int mi = 0; mi < 4; mi++)                             \
      _Pragma("unroll") for (int ni = 0; ni < 2; ni++) {                         \
        acc[MH * 4 + mi][NH * 2 + ni] = __builtin_amdgcn_mfma_f32_16x16x32_bf16( \
            aR[mi][0], bR[NH][ni][0], acc[MH * 4 + mi][NH * 2 + ni], 0, 0, 0);   \
        acc[MH * 4 + mi][NH * 2 + ni] = __builtin_amdgcn_mfma_f32_16x16x32_bf16( \
            aR[mi][1], bR[NH][ni][1], acc[MH * 4 + mi][NH * 2 + ni], 0, 0, 0);   \
      }                                                                          \
    __builtin_amdgcn_s_setprio(0);                                               \
    __builtin_amdgcn_s_barrier();                                                \
  }

__global__ __launch_bounds__(512, 2) void gemm_proj(const u16* __restrict__ A,
                                                    const u16* __restrict__ Bt,
                                                    u8* __restrict__ F8T,
                                                    float* __restrict__ F32,
                                                    const float* __restrict__ bias,
                                                    int K, int split, int ldcF) {
  // bijective XCD swizzle (nwg % 8 == 0 for both launches)
  int lin = blockIdx.y * 16 + blockIdx.x;
  int nwg = gridDim.y * 16;
  int cpx = nwg >> 3;
  int swz = (lin & 7) * cpx + (lin >> 3);
  int row0 = (swz & 15) * 256;
  int col0 = (swz >> 4) * 256;

  __shared__ u16 LA[2][2][8192];   // [dbuf][half][128 rows x 64 cols], 64 KB
  __shared__ u16 LB[2][2][8192];   // 64 KB

  int tid = threadIdx.x;
  int wave = tid >> 6, lane = tid & 63;
  int wm = wave >> 2, wn = wave & 3;
  int wm16 = wm * 16, wn16 = wn * 16;
  int lm = lane & 15, quad = lane >> 4;

  // staging: 512 lanes x 16B = 64 rows/load; 2 loads per 128-row half
  int r0 = tid >> 3;                           // 0..63
  int cg = (tid & 7) ^ (r0 & 7);               // pre-swizzled global chunk
  const u16* aSrc = A + (size_t)(row0 + r0) * K + cg * 8;
  const u16* bSrc = Bt + (size_t)(col0 + r0) * K + cg * 8;

  auto stA = [&](int d, int h, int kt) {
    const u16* p = aSrc + (size_t)h * 128 * K + (size_t)kt * 64;
    async16(p, &LA[d][h][wave * 512]);
    async16(p + (size_t)64 * K, &LA[d][h][4096 + wave * 512]);
  };
  auto stB = [&](int d, int h, int kt) {
    const u16* p = bSrc + (size_t)h * 128 * K + (size_t)kt * 64;
    async16(p, &LB[d][h][wave * 512]);
    async16(p + (size_t)64 * K, &LB[d][h][4096 + wave * 512]);
  };

  float4v acc[8][4] = {};
  short8 aR[4][2];        // current A-half fragments (32 VGPR)
  short8 bR[2][2][2];     // both B halves (32 VGPR)

  const int NT = K >> 6;       // K-tiles of 64 (12 or 32)
  const int NI = NT >> 1;      // iterations (2 K-tiles each), >= 2 here

  // prologue: d0 full tile kt0, d1.{B0,A0} kt1; drain d0 (leave d1 pair flying)
  stB(0, 0, 0); stA(0, 0, 0); stA(0, 1, 0); stB(0, 1, 0);
  stB(1, 0, 1); stA(1, 0, 1);
  VMW4;
  __builtin_amdgcn_s_barrier();

  for (int i = 0; i < NI - 1; i++) {
    int kt1 = 2 * i + 1, kt2 = 2 * i + 2, kt3 = 2 * i + 3;
    PH(0, 0, LDA_(0, 0), LDB_(0, 0), stA(1, 1, kt1), ((void)0));  // P1 d0(A0,B0)
    PH(0, 1, ((void)0),  LDB_(0, 1), stB(1, 1, kt1), ((void)0));  // P2 d0(A0,B1)
    PH(1, 1, LDA_(0, 1), ((void)0),  stB(0, 0, kt2), ((void)0));  // P3 d0(A1,B1)
    PH(1, 0, ((void)0),  ((void)0),  stA(0, 0, kt2), VMW4);       // P4 d0(A1,B0)
    PH(0, 0, LDA_(1, 0), LDB_(1, 0), stA(0, 1, kt2), ((void)0));  // P5 d1(A0,B0)
    PH(0, 1, ((void)0),  LDB_(1, 1), stB(0, 1, kt2), ((void)0));  // P6 d1(A0,B1)
    PH(1, 1, LDA_(1, 1), ((void)0),  stB(1, 0, kt3), ((void)0));  // P7 d1(A1,B1)
    PH(1, 0, ((void)0),  ((void)0),  stA(1, 0, kt3), VMW4);       // P8 d1(A1,B0)
  }
  {
    int kt1 = NT - 1;
    PH(0, 0, LDA_(0, 0), LDB_(0, 0), stA(1, 1, kt1), ((void)0));
    PH(0, 1, ((void)0),  LDB_(0, 1), stB(1, 1, kt1), ((void)0));
    PH(1, 1, LDA_(0, 1), ((void)0),  ((void)0),      ((void)0));
    PH(1, 0, ((void)0),  ((void)0),  ((void)0),      VMW0);
    PH(0, 0, LDA_(1, 0), LDB_(1, 0), ((void)0),      ((void)0));
    PH(0, 1, ((void)0),  LDB_(1, 1), ((void)0),      ((void)0));
    PH(1, 1, LDA_(1, 1), ((void)0),  ((void)0),      ((void)0));
    PH(1, 0, ((void)0),  ((void)0),  ((void)0),      ((void)0));
  }

  if (col0 < split) {
#pragma unroll
    for (int m = 0; m < 8; m++) {
#pragma unroll
      for (int n = 0; n < 4; n++) {
        int grow0 = row0 + m * 32 + wm16 + quad * 4;
        int gcol = col0 + n * 64 + wn16 + lm;
        unsigned pk = pk_fp8x4(acc[m][n][0], acc[m][n][1], acc[m][n][2], acc[m][n][3]);
        *(unsigned*)&F8T[(size_t)gcol * NN + grow0] = pk;
      }
    }
  } else {
#pragma unroll
    for (int m = 0; m < 8; m++) {
#pragma unroll
      for (int n = 0; n < 4; n++) {
#pragma unroll
        for (int r = 0; r < 4; r++) {
          int grow = row0 + m * 32 + wm16 + quad * 4 + r;
          int gcol = col0 + n * 64 + wn16 + lm - split;
          F32[(size_t)grow * ldcF + gcol] = acc[m][n][r] + bias[gcol];
        }
      }
    }
  }
}
#undef PH
#undef VMW4
#undef VMW0
#undef LDA_
#undef LDB_

// ------------------------------------------------- MX-fp8 GEMM, R11: 256x128 tile,
// BK=128, K=NN, 512 thr / 8 waves (2Mx4N), per-wave 128x32 C. 8-phase, register
// reuse: aR[4] (one A-half, reloaded Q1/Q3), bR[2] (both B halves, loaded Q1/Q2);
// 20 ds_read_b128 per wave per K-tile. Stage slots mirror gemm_proj; stA = 2
// async16 (16KB half), stB = 1 async16 (8KB half). vmcnt(3) at P4/P8 only
// (ledger: P4 drains through P2 -> d1 resident for P5-P8; P8 drains through P6
// -> d0(kt2) resident for next P1-P4; prologue VMW3 leaves d1.{B0,A0} flying;
// tail VMW0 at P4). LDS 96KB -> 1 block/CU. Unit scales (0x7F) = plain fp8.
// MODE 2: C[grow*ldc + coloff + gcol]; MODE 3: C[h*cStride + grow*ldc + gcol].
#define MXLDA_(CUR, MH)                                                          \
  _Pragma("unroll") for (int mi = 0; mi < 4; mi++) {                             \
    int lr = mi * 32 + wm16 + lm;                                                \
    int sw = lr & 7;                                                             \
    const u8* ap = &LA[CUR][MH][lr * 128];                                       \
    int4v lo = *(const int4v*)(ap + (((2 * quad) ^ sw) * 16));                   \
    int4v hi = *(const int4v*)(ap + (((2 * quad + 1) ^ sw) * 16));               \
    aR[mi][0] = lo[0]; aR[mi][1] = lo[1]; aR[mi][2] = lo[2]; aR[mi][3] = lo[3];  \
    aR[mi][4] = hi[0]; aR[mi][5] = hi[1]; aR[mi][6] = hi[2]; aR[mi][7] = hi[3];  \
  }

#define MXLDB_(CUR, NH)                                                          \
  {                                                                              \
    int lc = wn16 + lm;                                                          \
    int sw = lc & 7;                                                             \
    const u8* bp = &LB[CUR][NH][lc * 128];                                       \
    int4v lo = *(const int4v*)(bp + (((2 * quad) ^ sw) * 16));                   \
    int4v hi = *(const int4v*)(bp + (((2 * quad + 1) ^ sw) * 16));               \
    bR[NH][0] = lo[0]; bR[NH][1] = lo[1]; bR[NH][2] = lo[2]; bR[NH][3] = lo[3];  \
    bR[NH][4] = hi[0]; bR[NH][5] = hi[1]; bR[NH][6] = hi[2]; bR[NH][7] = hi[3];  \
  }

#define MXVMW3 asm volatile("s_waitcnt vmcnt(3)" ::: "memory")
#define MXVMW0 asm volatile("s_waitcnt vmcnt(0)" ::: "memory")

#define MXPH(MH, NH, LOADA, LOADB, STAGE, WAIT)                                  \
  {                                                                              \
    LOADA;                                                                       \
    LOADB;                                                                       \
    STAGE;                                                                       \
    WAIT;                                                                        \
    __builtin_amdgcn_s_barrier();                                                \
    __builtin_amdgcn_s_setprio(1);                                               \
    _Pragma("unroll") for (int mi = 0; mi < 4; mi++)                             \
      acc[MH * 4 + mi][NH] = __builtin_amdgcn_mfma_scale_f32_16x16x128_f8f6f4(   \
          aR[mi], bR[NH], acc[MH * 4 + mi][NH], 0, 0, 0, 127, 0, 127);           \
    __builtin_amdgcn_s_setprio(0);                                               \
    __builtin_amdgcn_s_barrier();                                                \
  }

template <int MODE>
__global__ __launch_bounds__(512, 2) void gemm_mx(const u8* __restrict__ A,
                                                  const u8* __restrict__ Bt,
                                                  float* __restrict__ Cout,
                                                  int ldc, int coloff_base, int coloff_step,
                                                  size_t bStride, size_t cStride) {
  constexpr int K = NN;
  int h = blockIdx.z;
  const u8* Ab = A + (size_t)h * ((size_t)NN * NN);
  const u8* Bb = Bt + (size_t)h * bStride;
  int row0 = blockIdx.x * 256;
  int col0 = blockIdx.y * 128;
  int coloff = coloff_base + h * coloff_step;

  __shared__ u8 LA[2][2][16384];   // [dbuf][half][128 rows x 128 k], 64 KB
  __shared__ u8 LB[2][2][8192];    // [dbuf][half][64 cols x 128 k], 32 KB

  int tid = threadIdx.x;
  int wave = tid >> 6, lane = tid & 63;
  int wm = wave >> 2, wn = wave & 3;
  int wm16 = wm * 16, wn16 = wn * 16;
  int lm = lane & 15, quad = lane >> 4;

  // staging: 512 lanes x 16B = 8KB/load = 64 rows of 128B
  int r0 = tid >> 3;                           // 0..63
  int cg = (tid & 7) ^ (r0 & 7);               // pre-swizzled global chunk
  const u8* aSrc = Ab + (size_t)(row0 + r0) * K + cg * 16;
  const u8* bSrc = Bb + (size_t)(col0 + r0) * K + cg * 16;

  auto stA = [&](int d, int hh, int kt) {      // 128-row half: 2 loads
    const u8* p = aSrc + (size_t)hh * 128 * K + (size_t)kt * 128;
    async16(p, &LA[d][hh][wave * 1024]);
    async16(p + (size_t)64 * K, &LA[d][hh][8192 + wave * 1024]);
  };
  auto stB = [&](int d, int hh, int kt) {      // 64-col half: 1 load
    const u8* p = bSrc + (size_t)hh * 64 * K + (size_t)kt * 128;
    async16(p, &LB[d][hh][wave * 1024]);
  };

  float4v acc[8][2] = {};
  int8v aR[4];           // current A-half fragments (32 VGPR)
  int8v bR[2];           // both B halves (16 VGPR)

  const int NT = K >> 7;       // 32 K-tiles of 128
  const int NI = NT >> 1;      // 16 iterations

  // prologue: d0 full tile kt0 (6 loads), d1.{B0,A0} kt1 (3 loads); drain d0
  stB(0, 0, 0); stA(0, 0, 0); stA(0, 1, 0); stB(0, 1, 0);
  stB(1, 0, 1); stA(1, 0, 1);
  MXVMW3;
  __builtin_amdgcn_s_barrier();

  for (int i = 0; i < NI - 1; i++) {
    int kt1 = 2 * i + 1, kt2 = 2 * i + 2, kt3 = 2 * i + 3;
    MXPH(0, 0, MXLDA_(0, 0), MXLDB_(0, 0), stA(1, 1, kt1), ((void)0)); // P1 d0(A0,B0)
    MXPH(0, 1, ((void)0),    MXLDB_(0, 1), stB(1, 1, kt1), ((void)0)); // P2 d0(A0,B1)
    MXPH(1, 1, MXLDA_(0, 1), ((void)0),    stB(0, 0, kt2), ((void)0)); // P3 d0(A1,B1)
    MXPH(1, 0, ((void)0),    ((void)0),    stA(0, 0, kt2), MXVMW3);    // P4 d0(A1,B0)
    MXPH(0, 0, MXLDA_(1, 0), MXLDB_(1, 0), stA(0, 1, kt2), ((void)0)); // P5 d1(A0,B0)
    MXPH(0, 1, ((void)0),    MXLDB_(1, 1), stB(0, 1, kt2), ((void)0)); // P6 d1(A0,B1)
    MXPH(1, 1, MXLDA_(1, 1), ((void)0),    stB(1, 0, kt3), ((void)0)); // P7 d1(A1,B1)
    MXPH(1, 0, ((void)0),    ((void)0),    stA(1, 0, kt3), MXVMW3);    // P8 d1(A1,B0)
  }
  {
    int kt1 = NT - 1;
    MXPH(0, 0, MXLDA_(0, 0), MXLDB_(0, 0), stA(1, 1, kt1), ((void)0));
    MXPH(0, 1, ((void)0),    MXLDB_(0, 1), stB(1, 1, kt1), ((void)0));
    MXPH(1, 1, MXLDA_(0, 1), ((void)0),    ((void)0),      ((void)0));
    MXPH(1, 0, ((void)0),    ((void)0),    ((void)0),      MXVMW0);
    MXPH(0, 0, MXLDA_(1, 0), MXLDB_(1, 0), ((void)0),      ((void)0));
    MXPH(0, 1, ((void)0),    MXLDB_(1, 1), ((void)0),      ((void)0));
    MXPH(1, 1, MXLDA_(1, 1), ((void)0),    ((void)0),      ((void)0));
    MXPH(1, 0, ((void)0),    ((void)0),    ((void)0),      ((void)0));
  }

#pragma unroll
  for (int m = 0; m < 8; m++) {
#pragma unroll
    for (int n = 0; n < 2; n++) {
#pragma unroll
      for (int r = 0; r < 4; r++) {
        int grow = row0 + m * 32 + wm16 + quad * 4 + r;
        int gcol = col0 + n * 64 + wn16 + lm;
        float v = acc[m][n][r];
        if constexpr (MODE == 2) {
          Cout[(size_t)grow * ldc + coloff + gcol] = v;
        } else {
          Cout[(size_t)h * cStride + (size_t)grow * ldc + gcol] = v;
        }
      }
    }
  }
}
#undef MXPH
#undef MXVMW3
#undef MXVMW0
#undef MXLDA_
#undef MXLDB_

// ------------------------------------------------- LN layer 0
__global__ __launch_bounds__(256) void ln0_kernel(const float* __restrict__ accin,
                                                  const float* __restrict__ rp,
                                                  const float* __restrict__ Lsum,
                                                  const float* __restrict__ g,
                                                  const float* __restrict__ b,
                                                  u16* __restrict__ h1b) {
  const int C = 2048;
  int n = blockIdx.x, tid = threadIdx.x;
  __shared__ float xs[2048];
  __shared__ float red[2][4];
  __shared__ float mrs[2];
  float linv[NHEADS];
#pragma unroll
  for (int h = 0; h < NHEADS; h++) linv[h] = 1.0f / Lsum[(size_t)h * NN + n];
  float sum = 0.f, sq = 0.f;
  const float* ar = accin + (size_t)n * C;
  const float* rr = rp + (size_t)n * C;
  for (int c = tid; c < C; c += 256) {
    float v = ar[c] * linv[c >> 9];
    v = v > 0.f ? v : (__expf(v) - 1.f);
    float x = v + rr[c];
    xs[c] = x; sum += x; sq += x * x;
  }
#pragma unroll
  for (int off = 32; off > 0; off >>= 1) { sum += __shfl_down(sum, off); sq += __shfl_down(sq, off); }
  if ((tid & 63) == 0) { red[0][tid >> 6] = sum; red[1][tid >> 6] = sq; }
  __syncthreads();
  if (tid == 0) {
    float s = red[0][0] + red[0][1] + red[0][2] + red[0][3];
    float q = red[1][0] + red[1][1] + red[1][2] + red[1][3];
    float mean = s / C, var = q / C - mean * mean;
    mrs[0] = mean; mrs[1] = rsqrtf(var + 1e-5f);
  }
  __syncthreads();
  float mean = mrs[0], rstd = mrs[1];
  for (int c = tid; c < C; c += 256) {
    float y = (xs[c] - mean) * rstd * g[c] + b[c];
    float z = y > 0.f ? y : (__expf(y) - 1.f);
    h1b[(size_t)n * C + c] = f2bf(z);
  }
}

// ------------------------------------------------- LN layer 1
__global__ __launch_bounds__(256) void ln1_kernel(const float* __restrict__ hp1,
                                                  const float* __restrict__ rp1,
                                                  const float* __restrict__ Lsum,
                                                  const float* __restrict__ g,
                                                  const float* __restrict__ b,
                                                  float* __restrict__ out) {
  const int C = 768;
  int n = blockIdx.x, tid = threadIdx.x;
  __shared__ float xs[768];
  __shared__ float red[2][4];
  __shared__ float mrs[2];
  float linv[NHEADS];
#pragma unroll
  for (int h = 0; h < NHEADS; h++) linv[h] = 0.25f / Lsum[(size_t)h * NN + n];
  float sum = 0.f, sq = 0.f;
  for (int c = tid; c < C; c += 256) {
    float x = hp1[((size_t)0 * NN + n) * C + c] * linv[0] +
              hp1[((size_t)1 * NN + n) * C + c] * linv[1] +
              hp1[((size_t)2 * NN + n) * C + c] * linv[2] +
              hp1[((size_t)3 * NN + n) * C + c] * linv[3];
    x += rp1[(size_t)n * C + c];     // bias already folded into rp1 by gemm_proj
    xs[c] = x; sum += x; sq += x * x;
  }
#pragma unroll
  for (int off = 32; off > 0; off >>= 1) { sum += __shfl_down(sum, off); sq += __shfl_down(sq, off); }
  if ((tid & 63) == 0) { red[0][tid >> 6] = sum; red[1][tid >> 6] = sq; }
  __syncthreads();
  if (tid == 0) {
    float s = red[0][0] + red[0][1] + red[0][2] + red[0][3];
    float q = red[1][0] + red[1][1] + red[1][2] + red[1][3];
    float mean = s / C, var = q / C - mean * mean;
    mrs[0] = mean; mrs[1] = rsqrtf(var + 1e-5f);
  }
  __syncthreads();
  float mean = mrs[0], rstd = mrs[1];
  for (int c = tid; c < C; c += 256)
    out[(size_t)n * C + c] = (xs[c] - mean) * rstd * g[c] + b[c];
}

// ============================================================================
extern "C" void kernel_launch(void* const* d_in, const int* in_sizes, int n_in,
                              void* d_out, int out_size, void* d_ws, size_t ws_size,
                              hipStream_t stream) {
  (void)in_sizes; (void)n_in; (void)out_size;
  const float* X    = (const float*)d_in[0];
  const int*   adj  = (const int*)d_in[1];
  const float* ew   = (const float*)d_in[2];
  const float* W0   = (const float*)d_in[3];
  const float* a0   = (const float*)d_in[4];
  const float* W1   = (const float*)d_in[5];
  const float* a1   = (const float*)d_in[6];
  const float* rp0w = (const float*)d_in[7];
  const float* rp0b = (const float*)d_in[8];
  const float* rp1w = (const float*)d_in[9];
  const float* rp1b = (const float*)d_in[10];
  const float* ln0g = (const float*)d_in[11];
  const float* ln0b = (const float*)d_in[12];
  const float* ln1g = (const float*)d_in[13];
  const float* ln1b = (const float*)d_in[14];
  float* out = (float*)d_out;
  char* wsb = (char*)d_ws;

  // ---- workspace layout (bytes) ----
  constexpr size_t OFF_XBF   = 0;             // [4096][768]    bf16   6291456
  constexpr size_t OFF_W0T   = 6291456;       // [2048][768]    bf16   3145728
  constexpr size_t OFF_RP0WT = 9437184;       // [2048][768]    bf16   3145728
  constexpr size_t OFF_W1T   = 12582912;      // [3072][2048]   bf16  12582912
  constexpr size_t OFF_RP1WT = 25165824;      // [768][2048]    bf16   3145728
  constexpr size_t OFF_WA0   = 28311552;
  constexpr size_t OFF_WA1   = 28336128;
  constexpr size_t OFF_S0    = 28401664;
  constexpr size_t OFF_S1    = 28532736;
  constexpr size_t OFF_L0    = 28664320;
  constexpr size_t OFF_L1    = 28729856;
  constexpr size_t OFF_H1B   = 28795392;      // [4096][2048] bf16   16777216
  constexpr size_t D         = 45572608;      // dynamic region
  constexpr size_t PD        = D + 50331648;          // P @ 95904256, 4 x 16777216 fp8
  constexpr size_t PN        = (size_t)NN * NN;
  constexpr size_t OFF_HP1   = PD + 4 * PN;           // [4][4096][768] f32 -> ends 213344768
  constexpr size_t OFF_MASK  = 213344768;             // [4096][64] u64 = 2097152 -> 215441920
  constexpr size_t OFF_SM0   = 215441920;             // [4] f32 (pad 256)
  constexpr size_t OFF_SM1   = 215442176;             // [4] f32

  u16*   XBF   = (u16*)(wsb + OFF_XBF);
  u16*   W0T   = (u16*)(wsb + OFF_W0T);
  u16*   RP0WT = (u16*)(wsb + OFF_RP0WT);
  u16*   W1T   = (u16*)(wsb + OFF_W1T);
  u16*   RP1WT = (u16*)(wsb + OFF_RP1WT);
  float* WA0   = (float*)(wsb + OFF_WA0);
  float* WA1   = (float*)(wsb + OFF_WA1);
  float* S0    = (float*)(wsb + OFF_S0);
  float* S1    = (float*)(wsb + OFF_S1);
  float* L0    = (float*)(wsb + OFF_L0);
  float* L1    = (float*)(wsb + OFF_L1);
  u16*   H1B   = (u16*)(wsb + OFF_H1B);
  u8*    WH0T  = (u8*)(wsb + D);
  float* RP0   = (float*)(wsb + D + 16777216);
  u8*    WH1T  = (u8*)(wsb + D);
  float* RP1   = (float*)(wsb + D + 25165824);
  u8*    P     = (u8*)(wsb + PD);
  float* HP1   = (float*)(wsb + OFF_HP1);
  float* ACC0  = (float*)(wsb + OFF_HP1);     // alias, layer-0 only
  u64*   MASK  = (u64*)(wsb + OFF_MASK);
  float* SM0   = (float*)(wsb + OFF_SM0);
  float* SM1   = (float*)(wsb + OFF_SM1);

  const int G = (ws_size >= OFF_HP1 + 50331648) ? 4 : 1;

  // ---- prep ----
  adj2bits<<<dim3(65536), 256, 0, stream>>>(adj, MASK);
  cast_f32_bf16<<<dim3((NN * 768 + 255) / 256), 256, 0, stream>>>(X, XBF, NN * 768);
  transcast_f32<<<dim3(16, 24, 4), 256, 0, stream>>>(W0, W0T, 768, 512);
  transcast_f32<<<dim3(24, 64, 4), 256, 0, stream>>>(W1, W1T, 2048, 768);
  transcast_f32<<<dim3(64, 24, 1), 256, 0, stream>>>(rp0w, RP0WT, 768, 2048);
  transcast_f32<<<dim3(24, 64, 1), 256, 0, stream>>>(rp1w, RP1WT, 2048, 768);

  // ---- layer 0 attention scalars (fp32 exact) ----
  wa_kernel<<<dim3(2 * NHEADS * 768 / 4), 256, 0, stream>>>(W0, a0, WA0, 768, 512);
  s8_kernel_f32<<<dim3(NN / 4), 256, 0, stream>>>(X, WA0, S0, 768);
  sdmax_kernel<<<dim3(NHEADS), 256, 0, stream>>>(S0, SM0);

  // ---- layer 0: merged projections (Wh0^T fp8 + RP0 fp32+bias), one launch ----
  gemm_proj<<<dim3(16, 16), 512, 0, stream>>>(XBF, W0T, WH0T, RP0, rp0b, 768, 2048, 2048);

  // per head-group: P' then ACC0[:, h*512:] = raw P'@Wh0 (MX-fp8, plain store)
  for (int g = 0; g < NHEADS; g += G) {
    if (G == 4) pexp_g_kernel<4><<<dim3(NN), 256, 0, stream>>>(MASK, ew, S0, SM0, P, L0, g);
    else        pexp_g_kernel<1><<<dim3(NN), 256, 0, stream>>>(MASK, ew, S0, SM0, P, L0, g);
    gemm_mx<2><<<dim3(16, 4, G), 512, 0, stream>>>(P, WH0T + (size_t)g * 512 * NN,
        ACC0, 2048, g * 512, 512, (size_t)512 * NN, 0);
  }
  ln0_kernel<<<dim3(NN), 256, 0, stream>>>(ACC0, RP0, L0, ln0g, ln0b, H1B);

  // ---- layer 1 attention scalars ----
  wa_kernel<<<dim3(2 * NHEADS * 2048 / 4), 256, 0, stream>>>(W1, a1, WA1, 2048, 768);
  s8_kernel_bf16<<<dim3(NN / 4), 256, 0, stream>>>(H1B, WA1, S1, 2048);
  sdmax_kernel<<<dim3(NHEADS), 256, 0, stream>>>(S1, SM1);

  // ---- layer 1: merged projections (Wh1^T fp8 + RP1 fp32+bias), one launch ----
  gemm_proj<<<dim3(16, 15), 512, 0, stream>>>(H1B, W1T, WH1T, RP1, rp1b, 2048, 3072, 768);

  // per head-group: P' then HP1[h] = raw P'@Wh1 (MX-fp8, plain store)
  for (int g = 0; g < NHEADS; g += G) {
    if (G == 4) pexp_g_kernel<4><<<dim3(NN), 256, 0, stream>>>(MASK, ew, S1, SM1, P, L1, g);
    else        pexp_g_kernel<1><<<dim3(NN), 256, 0, stream>>>(MASK, ew, S1, SM1, P, L1, g);
    gemm_mx<3><<<dim3(16, 6, G), 512, 0, stream>>>(P, WH1T + (size_t)g * 768 * NN,
        HP1 + (size_t)g * NN * 768, 768, 0, 0, (size_t)768 * NN, (size_t)NN * 768);
  }
  ln1_kernel<<<dim3(NN), 256, 0, stream>>>(HP1, RP1, L1, ln1g, ln1b, out);
}

// Round 8
// 578.161 us; speedup vs baseline: 1.0916x; 1.0916x over previous
//
#include <hip/hip_runtime.h>

// ============================================================================
// KnowledgeGraphEncoder: 2-layer dense GAT, N=4096, H=4.
// bf16 MFMA merged projection GEMMs; MX-fp8 (e4m3, unit scales) mfma_scale
// 16x16x128 attention GEMMs, BK=128; single-pass pexp with analytic row-max
// bound + 1-bit adjacency bitmask; fused 8-way s-kernels.
// R6-R10: gemm_proj = 256x256 8-phase schedule, register reuse, vmcnt at
// P4/P8 only. Best: 71us L1 proj, 0 bank conflicts.
// R11 (REVERTED): mx-256 8-phase port regressed (7.8M LDS bank conflicts,
// MfmaUtil 19%, 105us) — MX MFMA:LDS ratio differs from bf16; R5 mx structure
// (16 MFMA : 8 reads, 2 blocks/CU) is its balance point. gemm_mx restored to
// R5-exact.
// R12: s8 kernels vectorized (short8/float4 lane-contiguous loads, wa as
// float4 pairs) — Common-mistake #2; per-lane accumulation order changes
// (absmax drift ~1e-5, inside margin).
// ============================================================================

typedef unsigned short u16;
typedef unsigned char u8;
typedef unsigned long long u64;
using short8  = __attribute__((ext_vector_type(8))) short;
using float4v = __attribute__((ext_vector_type(4))) float;
using int4v   = __attribute__((ext_vector_type(4))) int;
using int8v   = __attribute__((ext_vector_type(8))) int;

#define NN 4096
#define NHEADS 4

__device__ __forceinline__ u16 f2bf(float f) {
  union { float f; unsigned u; } v; v.f = f;
  unsigned u = v.u;
  return (u16)((u + 0x7FFFu + ((u >> 16) & 1u)) >> 16);   // RNE
}
__device__ __forceinline__ float bf2f(u16 x) {
  union { unsigned u; float f; } v; v.u = ((unsigned)x) << 16; return v.f;
}
// pack 4 floats -> 4 fp8 e4m3 bytes (HW cvt, OCP on gfx950)
__device__ __forceinline__ unsigned pk_fp8x4(float a, float b, float c, float d) {
  int lo = __builtin_amdgcn_cvt_pk_fp8_f32(a, b, 0, false);
  return (unsigned)__builtin_amdgcn_cvt_pk_fp8_f32(c, d, lo, true);
}

// async global->LDS, 16B per lane, LDS dest = wave-uniform base + lane*16
__device__ __forceinline__ void async16(const void* g, void* l) {
  __builtin_amdgcn_global_load_lds(
      (const __attribute__((address_space(1))) unsigned int*)g,
      (__attribute__((address_space(3))) unsigned int*)l, 16, 0, 0);
}

// ---------------------------------------------------------------- cast fp32->bf16
__global__ __launch_bounds__(256) void cast_f32_bf16(const float* __restrict__ in,
                                                     u16* __restrict__ out, int n) {
  int i = blockIdx.x * 256 + threadIdx.x;
  if (i < n) out[i] = f2bf(in[i]);
}

// ------------------------------------------------- adj int32 -> bitmask (1 bit/entry)
__global__ __launch_bounds__(256) void adj2bits(const int* __restrict__ adj,
                                                u64* __restrict__ bits) {
  size_t gw = (size_t)blockIdx.x * 4 + (threadIdx.x >> 6);
  int lane = threadIdx.x & 63;
  int v = adj[gw * 64 + lane];
  u64 b = __ballot(v != 0);
  if (lane == 0) bits[gw] = b;
}

// ------------------------------------------------- transpose+cast fp32 -> bf16
// in [z][R][C] -> out [z][C][R]
__global__ __launch_bounds__(256) void transcast_f32(const float* __restrict__ in,
                                                     u16* __restrict__ out, int R, int C) {
  __shared__ float t[32][33];
  size_t zoff = (size_t)blockIdx.z * R * C;
  in += zoff; out += zoff;
  int c0 = blockIdx.x * 32, r0 = blockIdx.y * 32;
  int tx = threadIdx.x & 31, ty = threadIdx.x >> 5;
#pragma unroll
  for (int i = 0; i < 32; i += 8)
    t[ty + i][tx] = in[(size_t)(r0 + ty + i) * C + (c0 + tx)];
  __syncthreads();
#pragma unroll
  for (int i = 0; i < 32; i += 8)
    out[(size_t)(c0 + ty + i) * R + (r0 + tx)] = f2bf(t[tx][ty + i]);
}

// ------------------------------------------------- wa[side][h][f] = sum_o W[h][f][o]*a[h][side*O+o]
__global__ __launch_bounds__(256) void wa_kernel(const float* __restrict__ W,
                                                 const float* __restrict__ a,
                                                 float* __restrict__ wa, int F, int O) {
  int gw = blockIdx.x * 4 + (threadIdx.x >> 6);
  int lane = threadIdx.x & 63;
  int total = 2 * NHEADS * F;
  if (gw >= total) return;
  int side = gw / (NHEADS * F);
  int rem = gw - side * NHEADS * F;
  int h = rem / F, f = rem - h * F;
  const float* wrow = W + ((size_t)h * F + f) * O;
  const float* av = a + (size_t)h * 2 * O + (size_t)side * O;
  float s = 0.f;
  for (int o = lane; o < O; o += 64) s += wrow[o] * av[o];
#pragma unroll
  for (int off = 32; off > 0; off >>= 1) s += __shfl_down(s, off);
  if (lane == 0) wa[gw] = s;
}

// ------------------------------------------------- fused 8-way s: one wave per node
// R12: lane-contiguous float4 loads (F % 256 == 0 for both uses: 768, 2048).
__global__ __launch_bounds__(256) void s8_kernel_f32(const float* __restrict__ X,
                                                     const float* __restrict__ wa,
                                                     float* __restrict__ sout, int F) {
  int n = blockIdx.x * 4 + (threadIdx.x >> 6);
  int lane = threadIdx.x & 63;
  const float* x = X + (size_t)n * F;
  float acc[8] = {};
  for (int f0 = lane * 4; f0 < F; f0 += 256) {
    float4 xv = *(const float4*)(x + f0);
#pragma unroll
    for (int k = 0; k < 8; k++) {
      float4 w4 = *(const float4*)(wa + (size_t)k * F + f0);
      acc[k] += xv.x * w4.x + xv.y * w4.y + xv.z * w4.z + xv.w * w4.w;
    }
  }
#pragma unroll
  for (int k = 0; k < 8; k++) {
    float s = acc[k];
#pragma unroll
    for (int off = 32; off > 0; off >>= 1) s += __shfl_down(s, off);
    if (lane == 0) sout[(size_t)k * NN + n] = s;
  }
}

// R12: short8 bf16 loads (16B/lane), wa as float4 pairs. F % 512 == 0 (2048).
__global__ __launch_bounds__(256) void s8_kernel_bf16(const u16* __restrict__ X,
                                                      const float* __restrict__ wa,
                                                      float* __restrict__ sout, int F) {
  int n = blockIdx.x * 4 + (threadIdx.x >> 6);
  int lane = threadIdx.x & 63;
  const u16* x = X + (size_t)n * F;
  float acc[8] = {};
  for (int f0 = lane * 8; f0 < F; f0 += 512) {
    short8 xv = *(const short8*)(x + f0);
    float xf[8];
#pragma unroll
    for (int j = 0; j < 8; j++) xf[j] = bf2f((u16)xv[j]);
#pragma unroll
    for (int k = 0; k < 8; k++) {
      const float4* wp = (const float4*)(wa + (size_t)k * F + f0);
      float4 w0 = wp[0], w1 = wp[1];
      acc[k] += xf[0] * w0.x + xf[1] * w0.y + xf[2] * w0.z + xf[3] * w0.w +
                xf[4] * w1.x + xf[5] * w1.y + xf[6] * w1.z + xf[7] * w1.w;
    }
  }
#pragma unroll
  for (int k = 0; k < 8; k++) {
    float s = acc[k];
#pragma unroll
    for (int off = 32; off > 0; off >>= 1) s += __shfl_down(s, off);
    if (lane == 0) sout[(size_t)k * NN + n] = s;
  }
}

// ------------------------------------------------- sdmax[h] = max_n sdst[h][n]
__global__ __launch_bounds__(256) void sdmax_kernel(const float* __restrict__ s,
                                                    float* __restrict__ out) {
  int h = blockIdx.x, tid = threadIdx.x;
  const float* sd = s + (size_t)(NHEADS + h) * NN;
  float m = -3e38f;
  for (int i = tid; i < NN; i += 256) m = fmaxf(m, sd[i]);
  __shared__ float red[4];
#pragma unroll
  for (int off = 32; off > 0; off >>= 1) m = fmaxf(m, __shfl_down(m, off));
  if ((tid & 63) == 0) red[tid >> 6] = m;
  __syncthreads();
  if (tid == 0) out[h] = fmaxf(fmaxf(red[0], red[1]), fmaxf(red[2], red[3]));
}

// ------------------------------------------------- single-pass G-head P' = exp(v - m') fp8
template <int G>
__global__ __launch_bounds__(256) void pexp_g_kernel(const u64* __restrict__ mb,
                                                     const float* __restrict__ ew,
                                                     const float* __restrict__ s,
                                                     const float* __restrict__ sdmax,
                                                     u8* __restrict__ P,
                                                     float* __restrict__ L, int hb) {
  __shared__ u64 mrow[64];
  __shared__ float lred[G][4];
  int i = blockIdx.x, tid = threadIdx.x;
  if (tid < 64) mrow[tid] = mb[(size_t)i * 64 + tid];
  float sr[G], mp[G], lacc[G];
#pragma unroll
  for (int z = 0; z < G; z++) {
    sr[z] = s[(size_t)(hb + z) * NN + i];
    mp[z] = fmaxf(0.0f, sr[z] + sdmax[hb + z]);
    lacc[z] = 0.f;
  }
  const float4* wrow = (const float4*)(ew + (size_t)i * NN);
  __syncthreads();
  for (int jv = tid; jv < NN / 4; jv += 256) {
    float4 w = wrow[jv];
    int j0 = jv * 4;
    u64 mw = mrow[jv >> 4] >> (j0 & 63);
    float we[4]; we[0] = w.x; we[1] = w.y; we[2] = w.z; we[3] = w.w;
    bool m[4];
#pragma unroll
    for (int k = 0; k < 4; k++) m[k] = ((mw >> k) & 1ull) || (j0 + k == i);
#pragma unroll
    for (int z = 0; z < G; z++) {
      const float4 sd4 = *(const float4*)(s + (size_t)(NHEADS + hb + z) * NN + j0);
      float sd[4]; sd[0] = sd4.x; sd[1] = sd4.y; sd[2] = sd4.z; sd[3] = sd4.w;
      float p[4];
#pragma unroll
      for (int k = 0; k < 4; k++) {
        float x = sr[z] + sd[k];
        float e = x > 0.f ? x : 0.2f * x;
        float v = (m[k] ? e : -9e15f) * we[k];
        p[k] = __expf(v - mp[z]);
        lacc[z] += p[k];
      }
      *(unsigned*)(P + ((size_t)z * NN + i) * NN + j0) = pk_fp8x4(p[0], p[1], p[2], p[3]);
    }
  }
#pragma unroll
  for (int z = 0; z < G; z++) {
    float r = lacc[z];
#pragma unroll
    for (int off = 32; off > 0; off >>= 1) r += __shfl_down(r, off);
    if ((tid & 63) == 0) lred[z][tid >> 6] = r;
  }
  __syncthreads();
  if (tid < G)
    L[(size_t)(hb + tid) * NN + i] = lred[tid][0] + lred[tid][1] + lred[tid][2] + lred[tid][3];
}

// ------------------------------------------------- merged projection GEMM (R10 final)
#define LDA_(CUR, MH)                                                            \
  _Pragma("unroll") for (int mi = 0; mi < 4; mi++) {                             \
    int lr = mi * 32 + wm16 + lm;                                                \
    int sw = lr & 7;                                                             \
    const u16* ap = &LA[CUR][MH][lr * 64];                                       \
    aR[mi][0] = *(const short8*)(ap + ((quad ^ sw) * 8));                        \
    aR[mi][1] = *(const short8*)(ap + (((4 + quad) ^ sw) * 8));                  \
  }

#define LDB_(CUR, NH)                                                            \
  _Pragma("unroll") for (int ni = 0; ni < 2; ni++) {                             \
    int lc = ni * 64 + wn16 + lm;                                                \
    int sw = lc & 7;                                                             \
    const u16* bp = &LB[CUR][NH][lc * 64];                                       \
    bR[NH][ni][0] = *(const short8*)(bp + ((quad ^ sw) * 8));                    \
    bR[NH][ni][1] = *(const short8*)(bp + (((4 + quad) ^ sw) * 8));              \
  }

#define VMW4 asm volatile("s_waitcnt vmcnt(4)" ::: "memory")
#define VMW0 asm volatile("s_waitcnt vmcnt(0)" ::: "memory")

#define PH(MH, NH, LOADA, LOADB, STAGE, WAIT)                                    \
  {                                                                              \
    LOADA;                                                                       \
    LOADB;                                                                       \
    STAGE;                                                                       \
    WAIT;                                                                        \
    __builtin_amdgcn_s_barrier();                                                \
    __builtin_amdgcn_s_setprio(1);                                               \
    _Pragma("unroll") for (int mi = 0; mi < 4; mi++)                             \
      _Pragma("unroll") for (int ni = 0; ni < 2; ni++) {                         \
        acc[MH * 4 + mi][NH * 2 + ni] = __builtin_amdgcn_mfma_f32_16x16x32_bf16( \
            aR[mi][0], bR[NH][ni][0], acc[MH * 4 + mi][NH * 2 + ni], 0, 0, 0);   \
        acc[MH * 4 + mi][NH * 2 + ni] = __builtin_amdgcn_mfma_f32_16x16x32_bf16( \
            aR[mi][1], bR[NH][ni][1], acc[MH * 4 + mi][NH * 2 + ni], 0, 0, 0);   \
      }                                                                          \
    __builtin_amdgcn_s_setprio(0);                                               \
    __builtin_amdgcn_s_barrier();                                                \
  }

__global__ __launch_bounds__(512, 2) void gemm_proj(const u16* __restrict__ A,
                                                    const u16* __restrict__ Bt,
                                                    u8* __restrict__ F8T,
                                                    float* __restrict__ F32,
                                                    const float* __restrict__ bias,
                                                    int K, int split, int ldcF) {
  // bijective XCD swizzle (nwg % 8 == 0 for both launches)
  int lin = blockIdx.y * 16 + blockIdx.x;
  int nwg = gridDim.y * 16;
  int cpx = nwg >> 3;
  int swz = (lin & 7) * cpx + (lin >> 3);
  int row0 = (swz & 15) * 256;
  int col0 = (swz >> 4) * 256;

  __shared__ u16 LA[2][2][8192];   // [dbuf][half][128 rows x 64 cols], 64 KB
  __shared__ u16 LB[2][2][8192];   // 64 KB

  int tid = threadIdx.x;
  int wave = tid >> 6, lane = tid & 63;
  int wm = wave >> 2, wn = wave & 3;
  int wm16 = wm * 16, wn16 = wn * 16;
  int lm = lane & 15, quad = lane >> 4;

  // staging: 512 lanes x 16B = 64 rows/load; 2 loads per 128-row half
  int r0 = tid >> 3;                           // 0..63
  int cg = (tid & 7) ^ (r0 & 7);               // pre-swizzled global chunk
  const u16* aSrc = A + (size_t)(row0 + r0) * K + cg * 8;
  const u16* bSrc = Bt + (size_t)(col0 + r0) * K + cg * 8;

  auto stA = [&](int d, int h, int kt) {
    const u16* p = aSrc + (size_t)h * 128 * K + (size_t)kt * 64;
    async16(p, &LA[d][h][wave * 512]);
    async16(p + (size_t)64 * K, &LA[d][h][4096 + wave * 512]);
  };
  auto stB = [&](int d, int h, int kt) {
    const u16* p = bSrc + (size_t)h * 128 * K + (size_t)kt * 64;
    async16(p, &LB[d][h][wave * 512]);
    async16(p + (size_t)64 * K, &LB[d][h][4096 + wave * 512]);
  };

  float4v acc[8][4] = {};
  short8 aR[4][2];        // current A-half fragments (32 VGPR)
  short8 bR[2][2][2];     // both B halves (32 VGPR)

  const int NT = K >> 6;       // K-tiles of 64 (12 or 32)
  const int NI = NT >> 1;      // iterations (2 K-tiles each), >= 2 here

  // prologue: d0 full tile kt0, d1.{B0,A0} kt1; drain d0 (leave d1 pair flying)
  stB(0, 0, 0); stA(0, 0, 0); stA(0, 1, 0); stB(0, 1, 0);
  stB(1, 0, 1); stA(1, 0, 1);
  VMW4;
  __builtin_amdgcn_s_barrier();

  for (int i = 0; i < NI - 1; i++) {
    int kt1 = 2 * i + 1, kt2 = 2 * i + 2, kt3 = 2 * i + 3;
    PH(0, 0, LDA_(0, 0), LDB_(0, 0), stA(1, 1, kt1), ((void)0));  // P1 d0(A0,B0)
    PH(0, 1, ((void)0),  LDB_(0, 1), stB(1, 1, kt1), ((void)0));  // P2 d0(A0,B1)
    PH(1, 1, LDA_(0, 1), ((void)0),  stB(0, 0, kt2), ((void)0));  // P3 d0(A1,B1)
    PH(1, 0, ((void)0),  ((void)0),  stA(0, 0, kt2), VMW4);       // P4 d0(A1,B0)
    PH(0, 0, LDA_(1, 0), LDB_(1, 0), stA(0, 1, kt2), ((void)0));  // P5 d1(A0,B0)
    PH(0, 1, ((void)0),  LDB_(1, 1), stB(0, 1, kt2), ((void)0));  // P6 d1(A0,B1)
    PH(1, 1, LDA_(1, 1), ((void)0),  stB(1, 0, kt3), ((void)0));  // P7 d1(A1,B1)
    PH(1, 0, ((void)0),  ((void)0),  stA(1, 0, kt3), VMW4);       // P8 d1(A1,B0)
  }
  {
    int kt1 = NT - 1;
    PH(0, 0, LDA_(0, 0), LDB_(0, 0), stA(1, 1, kt1), ((void)0));
    PH(0, 1, ((void)0),  LDB_(0, 1), stB(1, 1, kt1), ((void)0));
    PH(1, 1, LDA_(0, 1), ((void)0),  ((void)0),      ((void)0));
    PH(1, 0, ((void)0),  ((void)0),  ((void)0),      VMW0);
    PH(0, 0, LDA_(1, 0), LDB_(1, 0), ((void)0),      ((void)0));
    PH(0, 1, ((void)0),  LDB_(1, 1), ((void)0),      ((void)0));
    PH(1, 1, LDA_(1, 1), ((void)0),  ((void)0),      ((void)0));
    PH(1, 0, ((void)0),  ((void)0),  ((void)0),      ((void)0));
  }

  if (col0 < split) {
#pragma unroll
    for (int m = 0; m < 8; m++) {
#pragma unroll
      for (int n = 0; n < 4; n++) {
        int grow0 = row0 + m * 32 + wm16 + quad * 4;
        int gcol = col0 + n * 64 + wn16 + lm;
        unsigned pk = pk_fp8x4(acc[m][n][0], acc[m][n][1], acc[m][n][2], acc[m][n][3]);
        *(unsigned*)&F8T[(size_t)gcol * NN + grow0] = pk;
      }
    }
  } else {
#pragma unroll
    for (int m = 0; m < 8; m++) {
#pragma unroll
      for (int n = 0; n < 4; n++) {
#pragma unroll
        for (int r = 0; r < 4; r++) {
          int grow = row0 + m * 32 + wm16 + quad * 4 + r;
          int gcol = col0 + n * 64 + wn16 + lm - split;
          F32[(size_t)grow * ldcF + gcol] = acc[m][n][r] + bias[gcol];
        }
      }
    }
  }
}
#undef PH
#undef VMW4
#undef VMW0
#undef LDA_
#undef LDB_

// ------------------------------------------------- 128x128 MX-fp8 GEMM, BK=128, K=NN
// R5 structure (RESTORED): 256 thr / 4 waves, double-buffered LDS, raw
// s_barrier + counted vmcnt(8) pipeline, 16 MFMA : 8 reads per wave per
// K-tile, 2 blocks/CU. mfma_scale with unit scales (0x7F) == plain fp8 math.
// MODE 2: C[grow*ldc + coloff_base + h*coloff_step + gcol]   (layer-0)
// MODE 3: C[h*cStride + grow*ldc + gcol]                     (layer-1)
template <int MODE>
__global__ __launch_bounds__(256) void gemm_mx(const u8* __restrict__ A,
                                               const u8* __restrict__ Bt,
                                               float* __restrict__ Cout,
                                               int ldc, int coloff_base, int coloff_step,
                                               size_t bStride, size_t cStride) {
  constexpr int K = NN;
  int h = blockIdx.z;
  const u8* Ab = A + (size_t)h * ((size_t)NN * NN);
  const u8* Bb = Bt + (size_t)h * bStride;
  int row0 = blockIdx.x * 128;
  int col0 = blockIdx.y * 128;
  int coloff = coloff_base + h * coloff_step;

  __shared__ u8 ldsA[2][128 * 128];   // 2 x 16 KB
  __shared__ u8 ldsB[2][128 * 128];   // 2 x 16 KB

  int tid = threadIdx.x;
  int wave = tid >> 6, lane = tid & 63;
  int wm = wave >> 1, wn = wave & 1;
  int lm = lane & 15, quad = lane >> 4;

  int sr = tid >> 3, sc = tid & 7;
  int scg = sc ^ (sr & 7);
  const u8* aPtr = Ab + (size_t)(row0 + sr) * K + scg * 16;
  const u8* bPtr = Bb + (size_t)(col0 + sr) * K + scg * 16;
  const size_t rowStep = (size_t)32 * K;

  float4v acc[4][4] = {};

  auto stage = [&](int buf, int k0) {
    u8* la = &ldsA[buf][wave * 1024];
    u8* lb = &ldsB[buf][wave * 1024];
#pragma unroll
    for (int b = 0; b < 4; b++) {
      async16(aPtr + k0 + b * rowStep, la + b * 4096);
      async16(bPtr + k0 + b * rowStep, lb + b * 4096);
    }
  };

  const int nt = K >> 7;                         // 32
  stage(0, 0);
  stage(1, 128);
  asm volatile("s_waitcnt vmcnt(8)" ::: "memory");   // tile 0 resident
  __builtin_amdgcn_s_barrier();
  __builtin_amdgcn_sched_barrier(0);

  for (int t = 0; t < nt; t++) {
    int cur = t & 1;
    const u8* LA = ldsA[cur];
    const u8* LB = ldsB[cur];
    int8v a32[4], b32[4];
#pragma unroll
    for (int s = 0; s < 4; s++) {
      int ra = wm * 64 + s * 16 + lm;
      int rb = wn * 64 + s * 16 + lm;
      int swa = ra & 7, swb = rb & 7;
      int4v alo = *(const int4v*)(&LA[ra * 128 + (((2 * quad) ^ swa) * 16)]);
      int4v ahi = *(const int4v*)(&LA[ra * 128 + (((2 * quad + 1) ^ swa) * 16)]);
      int4v blo = *(const int4v*)(&LB[rb * 128 + (((2 * quad) ^ swb) * 16)]);
      int4v bhi = *(const int4v*)(&LB[rb * 128 + (((2 * quad + 1) ^ swb) * 16)]);
      a32[s][0] = alo[0]; a32[s][1] = alo[1]; a32[s][2] = alo[2]; a32[s][3] = alo[3];
      a32[s][4] = ahi[0]; a32[s][5] = ahi[1]; a32[s][6] = ahi[2]; a32[s][7] = ahi[3];
      b32[s][0] = blo[0]; b32[s][1] = blo[1]; b32[s][2] = blo[2]; b32[s][3] = blo[3];
      b32[s][4] = bhi[0]; b32[s][5] = bhi[1]; b32[s][6] = bhi[2]; b32[s][7] = bhi[3];
    }
#pragma unroll
    for (int i = 0; i < 4; i++)
#pragma unroll
      for (int j = 0; j < 4; j++)
        acc[i][j] = __builtin_amdgcn_mfma_scale_f32_16x16x128_f8f6f4(
            a32[i], b32[j], acc[i][j], 0, 0, 0, 127, 0, 127);
    __builtin_amdgcn_s_barrier();
    __builtin_amdgcn_sched_barrier(0);
    if (t + 2 < nt) {
      stage(cur, (t + 2) << 7);
      asm volatile("s_waitcnt vmcnt(8)" ::: "memory");
    } else {
      asm volatile("s_waitcnt vmcnt(0)" ::: "memory");
    }
    __builtin_amdgcn_s_barrier();
    __builtin_amdgcn_sched_barrier(0);
  }

#pragma unroll
  for (int i = 0; i < 4; i++) {
#pragma unroll
    for (int j = 0; j < 4; j++) {
#pragma unroll
      for (int r = 0; r < 4; r++) {
        int grow = row0 + wm * 64 + i * 16 + quad * 4 + r;
        int gcol = col0 + wn * 64 + j * 16 + lm;
        float v = acc[i][j][r];
        if constexpr (MODE == 2) {
          Cout[(size_t)grow * ldc + coloff + gcol] = v;
        } else {
          Cout[(size_t)h * cStride + (size_t)grow * ldc + gcol] = v;
        }
      }
    }
  }
}

// ------------------------------------------------- LN layer 0
__global__ __launch_bounds__(256) void ln0_kernel(const float* __restrict__ accin,
                                                  const float* __restrict__ rp,
                                                  const float* __restrict__ Lsum,
                                                  const float* __restrict__ g,
                                                  const float* __restrict__ b,
                                                  u16* __restrict__ h1b) {
  const int C = 2048;
  int n = blockIdx.x, tid = threadIdx.x;
  __shared__ float xs[2048];
  __shared__ float red[2][4];
  __shared__ float mrs[2];
  float linv[NHEADS];
#pragma unroll
  for (int h = 0; h < NHEADS; h++) linv[h] = 1.0f / Lsum[(size_t)h * NN + n];
  float sum = 0.f, sq = 0.f;
  const float* ar = accin + (size_t)n * C;
  const float* rr = rp + (size_t)n * C;
  for (int c = tid; c < C; c += 256) {
    float v = ar[c] * linv[c >> 9];
    v = v > 0.f ? v : (__expf(v) - 1.f);
    float x = v + rr[c];
    xs[c] = x; sum += x; sq += x * x;
  }
#pragma unroll
  for (int off = 32; off > 0; off >>= 1) { sum += __shfl_down(sum, off); sq += __shfl_down(sq, off); }
  if ((tid & 63) == 0) { red[0][tid >> 6] = sum; red[1][tid >> 6] = sq; }
  __syncthreads();
  if (tid == 0) {
    float s = red[0][0] + red[0][1] + red[0][2] + red[0][3];
    float q = red[1][0] + red[1][1] + red[1][2] + red[1][3];
    float mean = s / C, var = q / C - mean * mean;
    mrs[0] = mean; mrs[1] = rsqrtf(var + 1e-5f);
  }
  __syncthreads();
  float mean = mrs[0], rstd = mrs[1];
  for (int c = tid; c < C; c += 256) {
    float y = (xs[c] - mean) * rstd * g[c] + b[c];
    float z = y > 0.f ? y : (__expf(y) - 1.f);
    h1b[(size_t)n * C + c] = f2bf(z);
  }
}

// ------------------------------------------------- LN layer 1
__global__ __launch_bounds__(256) void ln1_kernel(const float* __restrict__ hp1,
                                                  const float* __restrict__ rp1,
                                                  const float* __restrict__ Lsum,
                                                  const float* __restrict__ g,
                                                  const float* __restrict__ b,
                                                  float* __restrict__ out) {
  const int C = 768;
  int n = blockIdx.x, tid = threadIdx.x;
  __shared__ float xs[768];
  __shared__ float red[2][4];
  __shared__ float mrs[2];
  float linv[NHEADS];
#pragma unroll
  for (int h = 0; h < NHEADS; h++) linv[h] = 0.25f / Lsum[(size_t)h * NN + n];
  float sum = 0.f, sq = 0.f;
  for (int c = tid; c < C; c += 256) {
    float x = hp1[((size_t)0 * NN + n) * C + c] * linv[0] +
              hp1[((size_t)1 * NN + n) * C + c] * linv[1] +
              hp1[((size_t)2 * NN + n) * C + c] * linv[2] +
              hp1[((size_t)3 * NN + n) * C + c] * linv[3];
    x += rp1[(size_t)n * C + c];     // bias already folded into rp1 by gemm_proj
    xs[c] = x; sum += x; sq += x * x;
  }
#pragma unroll
  for (int off = 32; off > 0; off >>= 1) { sum += __shfl_down(sum, off); sq += __shfl_down(sq, off); }
  if ((tid & 63) == 0) { red[0][tid >> 6] = sum; red[1][tid >> 6] = sq; }
  __syncthreads();
  if (tid == 0) {
    float s = red[0][0] + red[0][1] + red[0][2] + red[0][3];
    float q = red[1][0] + red[1][1] + red[1][2] + red[1][3];
    float mean = s / C, var = q / C - mean * mean;
    mrs[0] = mean; mrs[1] = rsqrtf(var + 1e-5f);
  }
  __syncthreads();
  float mean = mrs[0], rstd = mrs[1];
  for (int c = tid; c < C; c += 256)
    out[(size_t)n * C + c] = (xs[c] - mean) * rstd * g[c] + b[c];
}

// ============================================================================
extern "C" void kernel_launch(void* const* d_in, const int* in_sizes, int n_in,
                              void* d_out, int out_size, void* d_ws, size_t ws_size,
                              hipStream_t stream) {
  (void)in_sizes; (void)n_in; (void)out_size;
  const float* X    = (const float*)d_in[0];
  const int*   adj  = (const int*)d_in[1];
  const float* ew   = (const float*)d_in[2];
  const float* W0   = (const float*)d_in[3];
  const float* a0   = (const float*)d_in[4];
  const float* W1   = (const float*)d_in[5];
  const float* a1   = (const float*)d_in[6];
  const float* rp0w = (const float*)d_in[7];
  const float* rp0b = (const float*)d_in[8];
  const float* rp1w = (const float*)d_in[9];
  const float* rp1b = (const float*)d_in[10];
  const float* ln0g = (const float*)d_in[11];
  const float* ln0b = (const float*)d_in[12];
  const float* ln1g = (const float*)d_in[13];
  const float* ln1b = (const float*)d_in[14];
  float* out = (float*)d_out;
  char* wsb = (char*)d_ws;

  // ---- workspace layout (bytes) ----
  constexpr size_t OFF_XBF   = 0;             // [4096][768]    bf16   6291456
  constexpr size_t OFF_W0T   = 6291456;       // [2048][768]    bf16   3145728
  constexpr size_t OFF_RP0WT = 9437184;       // [2048][768]    bf16   3145728
  constexpr size_t OFF_W1T   = 12582912;      // [3072][2048]   bf16  12582912
  constexpr size_t OFF_RP1WT = 25165824;      // [768][2048]    bf16   3145728
  constexpr size_t OFF_WA0   = 28311552;
  constexpr size_t OFF_WA1   = 28336128;
  constexpr size_t OFF_S0    = 28401664;
  constexpr size_t OFF_S1    = 28532736;
  constexpr size_t OFF_L0    = 28664320;
  constexpr size_t OFF_L1    = 28729856;
  constexpr size_t OFF_H1B   = 28795392;      // [4096][2048] bf16   16777216
  constexpr size_t D         = 45572608;      // dynamic region
  constexpr size_t PD        = D + 50331648;          // P @ 95904256, 4 x 16777216 fp8
  constexpr size_t PN        = (size_t)NN * NN;
  constexpr size_t OFF_HP1   = PD + 4 * PN;           // [4][4096][768] f32 -> ends 213344768
  constexpr size_t OFF_MASK  = 213344768;             // [4096][64] u64 = 2097152 -> 215441920
  constexpr size_t OFF_SM0   = 215441920;             // [4] f32 (pad 256)
  constexpr size_t OFF_SM1   = 215442176;             // [4] f32

  u16*   XBF   = (u16*)(wsb + OFF_XBF);
  u16*   W0T   = (u16*)(wsb + OFF_W0T);
  u16*   RP0WT = (u16*)(wsb + OFF_RP0WT);
  u16*   W1T   = (u16*)(wsb + OFF_W1T);
  u16*   RP1WT = (u16*)(wsb + OFF_RP1WT);
  float* WA0   = (float*)(wsb + OFF_WA0);
  float* WA1   = (float*)(wsb + OFF_WA1);
  float* S0    = (float*)(wsb + OFF_S0);
  float* S1    = (float*)(wsb + OFF_S1);
  float* L0    = (float*)(wsb + OFF_L0);
  float* L1    = (float*)(wsb + OFF_L1);
  u16*   H1B   = (u16*)(wsb + OFF_H1B);
  u8*    WH0T  = (u8*)(wsb + D);
  float* RP0   = (float*)(wsb + D + 16777216);
  u8*    WH1T  = (u8*)(wsb + D);
  float* RP1   = (float*)(wsb + D + 25165824);
  u8*    P     = (u8*)(wsb + PD);
  float* HP1   = (float*)(wsb + OFF_HP1);
  float* ACC0  = (float*)(wsb + OFF_HP1);     // alias, layer-0 only
  u64*   MASK  = (u64*)(wsb + OFF_MASK);
  float* SM0   = (float*)(wsb + OFF_SM0);
  float* SM1   = (float*)(wsb + OFF_SM1);

  const int G = (ws_size >= OFF_HP1 + 50331648) ? 4 : 1;

  // ---- prep ----
  adj2bits<<<dim3(65536), 256, 0, stream>>>(adj, MASK);
  cast_f32_bf16<<<dim3((NN * 768 + 255) / 256), 256, 0, stream>>>(X, XBF, NN * 768);
  transcast_f32<<<dim3(16, 24, 4), 256, 0, stream>>>(W0, W0T, 768, 512);
  transcast_f32<<<dim3(24, 64, 4), 256, 0, stream>>>(W1, W1T, 2048, 768);
  transcast_f32<<<dim3(64, 24, 1), 256, 0, stream>>>(rp0w, RP0WT, 768, 2048);
  transcast_f32<<<dim3(24, 64, 1), 256, 0, stream>>>(rp1w, RP1WT, 2048, 768);

  // ---- layer 0 attention scalars (fp32 exact) ----
  wa_kernel<<<dim3(2 * NHEADS * 768 / 4), 256, 0, stream>>>(W0, a0, WA0, 768, 512);
  s8_kernel_f32<<<dim3(NN / 4), 256, 0, stream>>>(X, WA0, S0, 768);
  sdmax_kernel<<<dim3(NHEADS), 256, 0, stream>>>(S0, SM0);

  // ---- layer 0: merged projections (Wh0^T fp8 + RP0 fp32+bias), one launch ----
  gemm_proj<<<dim3(16, 16), 512, 0, stream>>>(XBF, W0T, WH0T, RP0, rp0b, 768, 2048, 2048);

  // per head-group: P' then ACC0[:, h*512:] = raw P'@Wh0 (MX-fp8, plain store)
  for (int g = 0; g < NHEADS; g += G) {
    if (G == 4) pexp_g_kernel<4><<<dim3(NN), 256, 0, stream>>>(MASK, ew, S0, SM0, P, L0, g);
    else        pexp_g_kernel<1><<<dim3(NN), 256, 0, stream>>>(MASK, ew, S0, SM0, P, L0, g);
    gemm_mx<2><<<dim3(32, 4, G), 256, 0, stream>>>(P, WH0T + (size_t)g * 512 * NN,
        ACC0, 2048, g * 512, 512, (size_t)512 * NN, 0);
  }
  ln0_kernel<<<dim3(NN), 256, 0, stream>>>(ACC0, RP0, L0, ln0g, ln0b, H1B);

  // ---- layer 1 attention scalars ----
  wa_kernel<<<dim3(2 * NHEADS * 2048 / 4), 256, 0, stream>>>(W1, a1, WA1, 2048, 768);
  s8_kernel_bf16<<<dim3(NN / 4), 256, 0, stream>>>(H1B, WA1, S1, 2048);
  sdmax_kernel<<<dim3(NHEADS), 256, 0, stream>>>(S1, SM1);

  // ---- layer 1: merged projections (Wh1^T fp8 + RP1 fp32+bias), one launch ----
  gemm_proj<<<dim3(16, 15), 512, 0, stream>>>(H1B, W1T, WH1T, RP1, rp1b, 2048, 3072, 768);

  // per head-group: P' then HP1[h] = raw P'@Wh1 (MX-fp8, plain store)
  for (int g = 0; g < NHEADS; g += G) {
    if (G == 4) pexp_g_kernel<4><<<dim3(NN), 256, 0, stream>>>(MASK, ew, S1, SM1, P, L1, g);
    else        pexp_g_kernel<1><<<dim3(NN), 256, 0, stream>>>(MASK, ew, S1, SM1, P, L1, g);
    gemm_mx<3><<<dim3(32, 6, G), 256, 0, stream>>>(P, WH1T + (size_t)g * 768 * NN,
        HP1 + (size_t)g * NN * 768, 768, 0, 0, (size_t)768 * NN, (size_t)NN * 768);
  }
  ln1_kernel<<<dim3(NN), 256, 0, stream>>>(HP1, RP1, L1, ln1g, ln1b, out);
}